// Round 3
// baseline (3893.320 us; speedup 1.0000x reference)
//
#include <hip/hip_runtime.h>
#include <hip/hip_bf16.h>

// Problem constants
#define BB   4096
#define TT   128
#define OBS  64
#define ACT  16
#define DD   64
#define HH   256
#define G4   1024   // 4*H
#define BD   262144 // B*D

typedef short bshort8 __attribute__((ext_vector_type(8)));
typedef float f32x4  __attribute__((ext_vector_type(4)));

__device__ __forceinline__ unsigned short f2bf(float f) {
    union { float f; unsigned int u; } v; v.f = f;
    unsigned int u = v.u;
    u += 0x7FFFu + ((u >> 16) & 1u);   // RNE
    return (unsigned short)(u >> 16);
}
__device__ __forceinline__ float bf2f(unsigned short s) {
    union { unsigned int u; float f; } v; v.u = ((unsigned int)s) << 16;
    return v.f;
}

// ---------------- pack weights: Wt[ko][col][j] = B[8*ko+j][col], bf16 -------
__global__ void pack_wt(const float* __restrict__ Wx, const float* __restrict__ Wh,
                        unsigned short* __restrict__ wt) {
    int idx = blockIdx.x * 256 + threadIdx.x;      // < 40*1024*8 = 327680
    int j   = idx & 7;
    int col = (idx >> 3) & 1023;
    int ko  = idx >> 13;
    int k   = ko * 8 + j;
    float v = (k < 64) ? Wx[k * 1024 + col] : Wh[(k - 64) * 1024 + col];
    wt[idx] = f2bf(v);
}

// ---------------- embed: one block per batch row b, all 128 timesteps -------
__global__ void __launch_bounds__(256)
embed_tiled(const float* __restrict__ obs, const float* __restrict__ act,
            const float* __restrict__ We,  const float* __restrict__ be,
            unsigned short* __restrict__ x) {
    int b   = blockIdx.x;
    int tid = threadIdx.x;
    __shared__ __align__(16) float A[128 * 84];
    __shared__ __align__(16) float W[80 * 64];

    for (int i = tid; i < 1280; i += 256)
        *reinterpret_cast<f32x4*>(&W[i * 4]) = *reinterpret_cast<const f32x4*>(&We[i * 4]);
    const float* ob = obs + (size_t)b * (TT * OBS);
#pragma unroll
    for (int it = 0; it < 8; ++it) {
        int i4 = tid + it * 256;
        f32x4 v = *reinterpret_cast<const f32x4*>(ob + i4 * 4);
        int e = i4 * 4, t = e >> 6, f = e & 63;
        *reinterpret_cast<f32x4*>(&A[t * 84 + f]) = v;
    }
    const float* ar = act + (size_t)b * (TT * ACT);
#pragma unroll
    for (int it = 0; it < 2; ++it) {
        int i4 = tid + it * 256;
        f32x4 v = *reinterpret_cast<const f32x4*>(ar + i4 * 4);
        int e = i4 * 4, t = e >> 4, f = e & 15;
        *reinterpret_cast<f32x4*>(&A[t * 84 + 64 + f]) = v;
    }
    __syncthreads();

    int rg = tid & 15, cg = tid >> 4;
    int c0 = cg * 4;
    float acc[8][4];
    float be0 = be[c0], be1 = be[c0 + 1], be2 = be[c0 + 2], be3 = be[c0 + 3];
#pragma unroll
    for (int i = 0; i < 8; ++i) {
        acc[i][0] = be0; acc[i][1] = be1; acc[i][2] = be2; acc[i][3] = be3;
    }

    for (int kq = 0; kq < 20; ++kq) {
        f32x4 A4[8];
#pragma unroll
        for (int i = 0; i < 8; ++i)
            A4[i] = *reinterpret_cast<const f32x4*>(&A[(rg + 16 * i) * 84 + kq * 4]);
        f32x4 W0 = *reinterpret_cast<const f32x4*>(&W[(kq * 4 + 0) * 64 + c0]);
        f32x4 W1 = *reinterpret_cast<const f32x4*>(&W[(kq * 4 + 1) * 64 + c0]);
        f32x4 W2 = *reinterpret_cast<const f32x4*>(&W[(kq * 4 + 2) * 64 + c0]);
        f32x4 W3 = *reinterpret_cast<const f32x4*>(&W[(kq * 4 + 3) * 64 + c0]);
#pragma unroll
        for (int i = 0; i < 8; ++i) {
#pragma unroll
            for (int j = 0; j < 4; ++j) {
                acc[i][j] += A4[i][0] * W0[j] + A4[i][1] * W1[j]
                           + A4[i][2] * W2[j] + A4[i][3] * W3[j];
            }
        }
    }

#pragma unroll
    for (int i = 0; i < 8; ++i) {
        int t = rg + 16 * i;
        unsigned int lo = (unsigned)f2bf(acc[i][0]) | ((unsigned)f2bf(acc[i][1]) << 16);
        unsigned int hi = (unsigned)f2bf(acc[i][2]) | ((unsigned)f2bf(acc[i][3]) << 16);
        *reinterpret_cast<uint2*>(x + ((size_t)t * BB + b) * DD + c0) = make_uint2(lo, hi);
    }
}

// ---------------- BN partial stats from bf16 x: p[t][slice][64] -------------
__global__ void stats_x(const unsigned short* __restrict__ x,
                        float* __restrict__ p1, float* __restrict__ p2) {
    int t = blockIdx.x, s = blockIdx.y;
    int tid = threadIdx.x;
    int dg = tid & 15, bl = tid >> 4;
    int d0 = dg * 4;
    float s1[4] = {0, 0, 0, 0}, s2[4] = {0, 0, 0, 0};
    const unsigned short* xt = x + (size_t)t * BB * DD;
    for (int it = 0; it < 32; ++it) {
        int b = s * 512 + it * 16 + bl;
        uint2 v = *reinterpret_cast<const uint2*>(xt + (size_t)b * DD + d0);
        const unsigned short* u = reinterpret_cast<const unsigned short*>(&v);
#pragma unroll
        for (int q = 0; q < 4; ++q) {
            float xv = bf2f(u[q]);
            s1[q] += xv; s2[q] += xv * xv;
        }
    }
    __shared__ float r1[16][64];
    __shared__ float r2[16][64];
#pragma unroll
    for (int q = 0; q < 4; ++q) { r1[bl][d0 + q] = s1[q]; r2[bl][d0 + q] = s2[q]; }
    __syncthreads();
    if (tid < 64) {
        float a = 0.f, b2 = 0.f;
        for (int g = 0; g < 16; ++g) { a += r1[g][tid]; b2 += r2[g][tid]; }
        size_t o = ((size_t)t * 8 + s) * 64 + tid;
        p1[o] = a; p2[o] = b2;
    }
}

// ---------------- BN stats finalize: a = rstd*scale, bb = bias - m*a ---------
__global__ void bn_stats(const float* __restrict__ p1, const float* __restrict__ p2,
                         const float* __restrict__ scale, const float* __restrict__ bias,
                         float* __restrict__ sa, float* __restrict__ sb) {
    int t = blockIdx.x, d = threadIdx.x;  // 64 threads
    float s1 = 0.f, s2 = 0.f;
    for (int c = 0; c < 8; ++c) {
        size_t o = ((size_t)t * 8 + c) * 64 + d;
        s1 += p1[o]; s2 += p2[o];
    }
    float m   = s1 * (1.0f / 4096.0f);
    float var = s2 * (1.0f / 4096.0f) - m * m;
    float a   = rsqrtf(var + 1e-5f) * scale[d];
    sa[t * 64 + d] = a;
    sb[t * 64 + d] = bias[d] - m * a;
}

// ---------------- persistent LSTM: all 128 steps, flag-synced ----------------
// grid 256 blocks: 64 row-groups (64 rows) x 4 hidden-groups (64 u).
// 84KB dynamic LDS forces 1 block/CU -> all 256 co-resident (deadlock-free).
// c state lives in registers. BN+leakyReLU folded into per-step x staging.
__global__ void __launch_bounds__(256)
lstm_persist(const unsigned short* __restrict__ x, const unsigned short* __restrict__ wt,
             const float* __restrict__ sa, const float* __restrict__ sb,
             unsigned short* __restrict__ h0, unsigned short* __restrict__ h1,
             const float* __restrict__ b_lstm, unsigned int* __restrict__ flags) {
    extern __shared__ __align__(16) unsigned short A[];   // [64 rows][328]

    int bid  = blockIdx.x;
    int xcd  = bid & 7;
    int slot = bid >> 3;
    int rg   = xcd * 8 + (slot >> 2);  // 0..63 — peers of a group share an XCD
    int cg   = slot & 3;               // 0..3
    int tid  = threadIdx.x;

    int lane = tid & 63, w = tid >> 6;
    int l15 = lane & 15, lhi = lane >> 4;
    int u = cg * 64 + w * 16 + l15;    // hidden index 0..255

    unsigned int* flag = flags + rg * 32;

    float bl0 = b_lstm[u], bl1 = b_lstm[256 + u], bl2 = b_lstm[512 + u], bl3 = b_lstm[768 + u];

    float creg[4][4];
#pragma unroll
    for (int rf = 0; rf < 4; ++rf)
#pragma unroll
        for (int r = 0; r < 4; ++r) creg[rf][r] = 0.f;

    // x-staging thread mapping: oct fixed per thread -> preload BN coeffs once per t
    int xoct = tid & 7;        // d-oct
    int d0x  = xoct * 8;

    for (int t = 0; t < TT; ++t) {
        // ---- wait for peers' h_{t-1} (and buffer anti-dep) ----
        if (t > 0 && tid == 0) {
            unsigned int target = 4u * (unsigned)t;
            while (__hip_atomic_load(flag, __ATOMIC_ACQUIRE, __HIP_MEMORY_SCOPE_AGENT) < target)
                __builtin_amdgcn_s_sleep(1);
        }
        __syncthreads();

        const unsigned short* hread = (t & 1) ? h1 : h0;
        unsigned short*       hwrit = (t & 1) ? h0 : h1;

        // ---- stage x_t rows with BN + leakyReLU fold (k = 0..63) ----
        {
            f32x4 a0 = *reinterpret_cast<const f32x4*>(sa + t * 64 + d0x);
            f32x4 a1 = *reinterpret_cast<const f32x4*>(sa + t * 64 + d0x + 4);
            f32x4 b0 = *reinterpret_cast<const f32x4*>(sb + t * 64 + d0x);
            f32x4 b1 = *reinterpret_cast<const f32x4*>(sb + t * 64 + d0x + 4);
            const unsigned short* xs = x + ((size_t)t * BB + rg * 64) * DD;
#pragma unroll
            for (int it = 0; it < 2; ++it) {
                int idx = tid + it * 256;      // < 512
                int row = idx >> 3;
                uint4 v = *reinterpret_cast<const uint4*>(xs + row * DD + d0x);
                unsigned short* uu = reinterpret_cast<unsigned short*>(&v);
#pragma unroll
                for (int q = 0; q < 4; ++q) {
                    float y = a0[q] * bf2f(uu[q]) + b0[q];
                    uu[q] = f2bf(y >= 0.f ? y : 0.2f * y);
                }
#pragma unroll
                for (int q = 0; q < 4; ++q) {
                    float y = a1[q] * bf2f(uu[4 + q]) + b1[q];
                    uu[4 + q] = f2bf(y >= 0.f ? y : 0.2f * y);
                }
                *reinterpret_cast<uint4*>(&A[row * 328 + xoct * 8]) = v;
            }
        }
        // ---- stage h_{t-1} rows (k = 64..319) ----
        {
            const unsigned short* hs = hread + (size_t)rg * 64 * HH;
#pragma unroll
            for (int it = 0; it < 8; ++it) {
                int idx = tid + it * 256;      // < 2048
                int row = idx >> 5, kk = idx & 31;
                *reinterpret_cast<uint4*>(&A[row * 328 + 64 + kk * 8]) =
                    *reinterpret_cast<const uint4*>(hs + row * HH + kk * 8);
            }
        }
        __syncthreads();

        // ---- GEMM: z = A @ Wslice ----
        f32x4 acc[4][4];
#pragma unroll
        for (int rf = 0; rf < 4; ++rf)
#pragma unroll
            for (int g = 0; g < 4; ++g) acc[rf][g] = (f32x4)0.f;

#pragma unroll
        for (int ko2 = 0; ko2 < 10; ++ko2) {
            int ko = ko2 * 4 + lhi;
            bshort8 a[4], bfr[4];
#pragma unroll
            for (int rf = 0; rf < 4; ++rf)
                a[rf] = *reinterpret_cast<const bshort8*>(&A[(rf * 16 + l15) * 328 + ko * 8]);
#pragma unroll
            for (int g = 0; g < 4; ++g)
                bfr[g] = *reinterpret_cast<const bshort8*>(wt + ((size_t)ko * 1024 + g * 256 + u) * 8);
#pragma unroll
            for (int rf = 0; rf < 4; ++rf)
#pragma unroll
                for (int g = 0; g < 4; ++g)
                    acc[rf][g] = __builtin_amdgcn_mfma_f32_16x16x32_bf16(a[rf], bfr[g], acc[rf][g], 0, 0, 0);
        }

        // ---- gates + state update (c in registers) ----
#pragma unroll
        for (int rf = 0; rf < 4; ++rf) {
#pragma unroll
            for (int r = 0; r < 4; ++r) {
                int brow = rg * 64 + rf * 16 + lhi * 4 + r;
                float zi = acc[rf][0][r] + bl0;
                float zf = acc[rf][1][r] + bl1;
                float zg = acc[rf][2][r] + bl2;
                float zo = acc[rf][3][r] + bl3;
                float si = 1.f / (1.f + __expf(-zi));
                float sf = 1.f / (1.f + __expf(-zf));
                float so = 1.f / (1.f + __expf(-zo));
                float tg = 2.f / (1.f + __expf(-2.f * zg)) - 1.f;
                float cn = sf * creg[rf][r] + si * tg;
                float tc = 2.f / (1.f + __expf(-2.f * cn)) - 1.f;
                creg[rf][r] = cn;
                hwrit[(size_t)brow * HH + u] = f2bf(so * tc);
            }
        }

        // ---- publish h_t ----
        __threadfence();
        __syncthreads();
        if (tid == 0)
            __hip_atomic_fetch_add(flag, 1u, __ATOMIC_RELEASE, __HIP_MEMORY_SCOPE_AGENT);
    }
}

// ---------------- heads: mu = h@Wmu + bmu ; log_std clipped ------------------
__global__ void heads(const unsigned short* __restrict__ h,
                      const float* __restrict__ Wmu, const float* __restrict__ bmu,
                      const float* __restrict__ Wls, const float* __restrict__ bls,
                      float* __restrict__ out) {
    int tid = threadIdx.x;
    int b = blockIdx.x * 4 + (tid >> 6);
    int d = tid & 63;
    const unsigned short* hr = h + (size_t)b * HH;
    float mu = 0.f, ls = 0.f;
    for (int k = 0; k < HH; ++k) {
        float hv = bf2f(hr[k]);
        mu += hv * Wmu[k * 64 + d];
        ls += hv * Wls[k * 64 + d];
    }
    mu += bmu[d];
    ls += bls[d];
    ls = fminf(fmaxf(ls, -10.f), 2.f);
    out[(size_t)b * 64 + d] = mu;
    out[BD + (size_t)b * 64 + d] = ls;
}

extern "C" void kernel_launch(void* const* d_in, const int* in_sizes, int n_in,
                              void* d_out, int out_size, void* d_ws, size_t ws_size,
                              hipStream_t stream) {
    const float* obs = (const float*)d_in[0];
    const float* act = (const float*)d_in[1];
    const float* We  = (const float*)d_in[2];
    const float* be  = (const float*)d_in[3];
    const float* bns = (const float*)d_in[4];
    const float* bnb = (const float*)d_in[5];
    const float* Wx  = (const float*)d_in[6];
    const float* Wh  = (const float*)d_in[7];
    const float* bl  = (const float*)d_in[8];
    const float* Wmu = (const float*)d_in[9];
    const float* bmu = (const float*)d_in[10];
    const float* Wls = (const float*)d_in[11];
    const float* bls = (const float*)d_in[12];

    char* ws = (char*)d_ws;
    unsigned short* xbf = (unsigned short*)(ws + 0);            // 64MB (raw pre-BN bf16)
    unsigned short* wt  = (unsigned short*)(ws + 67108864);     // 640KB
    unsigned short* h0  = (unsigned short*)(ws + 67764224);     // 2MB
    unsigned short* h1  = (unsigned short*)(ws + 69861376);     // 2MB
    unsigned int*  flags = (unsigned int*)(ws + 71958528);      // 64*32*4 = 8KB
    float* p1           = (float*)(ws + 76152832);              // 64KB
    float* p2           = (float*)(ws + 78249984);              // 64KB
    float* sa           = (float*)(ws + 80347136);              // 32KB
    float* sb           = (float*)(ws + 80379904);

    hipMemsetAsync(h0, 0, (size_t)BB * HH * 2, stream);
    hipMemsetAsync(flags, 0, 64 * 32 * 4, stream);

    pack_wt<<<1280, 256, 0, stream>>>(Wx, Wh, wt);
    embed_tiled<<<4096, 256, 0, stream>>>(obs, act, We, be, xbf);
    stats_x<<<dim3(128, 8), 256, 0, stream>>>(xbf, p1, p2);
    bn_stats<<<128, 64, 0, stream>>>(p1, p2, bns, bnb, sa, sb);

    lstm_persist<<<256, 256, 86016, stream>>>(xbf, wt, sa, sb, h0, h1, bl, flags);

    heads<<<1024, 256, 0, stream>>>(h0, Wmu, bmu, Wls, bls, (float*)d_out);
}

// Round 4
// 2726.879 us; speedup vs baseline: 1.4278x; 1.4278x over previous
//
#include <hip/hip_runtime.h>
#include <hip/hip_bf16.h>

// Problem constants
#define BB   4096
#define TT   128
#define OBS  64
#define ACT  16
#define DD   64
#define HH   256
#define G4   1024   // 4*H
#define BD   262144 // B*D

// LDS A-tile row stride in shorts: 320 data + 4 pad; 324 % 64 == 4 so
// row-to-row bank shift = 2 -> b128 reads are the inherent 8-cycle minimum.
#define ASTR 324

typedef short bshort8 __attribute__((ext_vector_type(8)));
typedef float f32x4  __attribute__((ext_vector_type(4)));

__device__ __forceinline__ unsigned short f2bf(float f) {
    union { float f; unsigned int u; } v; v.f = f;
    unsigned int u = v.u;
    u += 0x7FFFu + ((u >> 16) & 1u);   // RNE
    return (unsigned short)(u >> 16);
}
__device__ __forceinline__ float bf2f(unsigned short s) {
    union { unsigned int u; float f; } v; v.u = ((unsigned int)s) << 16;
    return v.f;
}

// ---------------- pack weights: Wt[ko][col][j] = B[8*ko+j][col], bf16 -------
// B = [Wx (64 rows) ; Wh (256 rows)] -> K = 320 = 40 k-octs, 1024 cols
__global__ void pack_wt(const float* __restrict__ Wx, const float* __restrict__ Wh,
                        unsigned short* __restrict__ wt) {
    int idx = blockIdx.x * 256 + threadIdx.x;      // < 40*1024*8 = 327680
    int j   = idx & 7;
    int col = (idx >> 3) & 1023;
    int ko  = idx >> 13;
    int k   = ko * 8 + j;
    float v = (k < 64) ? Wx[k * 1024 + col] : Wh[(k - 64) * 1024 + col];
    wt[idx] = f2bf(v);
}

// ---------------- embed: one block per batch row b, all 128 timesteps -------
__global__ void __launch_bounds__(256)
embed_tiled(const float* __restrict__ obs, const float* __restrict__ act,
            const float* __restrict__ We,  const float* __restrict__ be,
            unsigned short* __restrict__ x) {
    int b   = blockIdx.x;
    int tid = threadIdx.x;
    __shared__ __align__(16) float A[128 * 84];
    __shared__ __align__(16) float W[80 * 64];

    for (int i = tid; i < 1280; i += 256)
        *reinterpret_cast<f32x4*>(&W[i * 4]) = *reinterpret_cast<const f32x4*>(&We[i * 4]);
    const float* ob = obs + (size_t)b * (TT * OBS);
#pragma unroll
    for (int it = 0; it < 8; ++it) {
        int i4 = tid + it * 256;
        f32x4 v = *reinterpret_cast<const f32x4*>(ob + i4 * 4);
        int e = i4 * 4, t = e >> 6, f = e & 63;
        *reinterpret_cast<f32x4*>(&A[t * 84 + f]) = v;
    }
    const float* ar = act + (size_t)b * (TT * ACT);
#pragma unroll
    for (int it = 0; it < 2; ++it) {
        int i4 = tid + it * 256;
        f32x4 v = *reinterpret_cast<const f32x4*>(ar + i4 * 4);
        int e = i4 * 4, t = e >> 4, f = e & 15;
        *reinterpret_cast<f32x4*>(&A[t * 84 + 64 + f]) = v;
    }
    __syncthreads();

    int rg = tid & 15, cg = tid >> 4;
    int c0 = cg * 4;
    float acc[8][4];
    float be0 = be[c0], be1 = be[c0 + 1], be2 = be[c0 + 2], be3 = be[c0 + 3];
#pragma unroll
    for (int i = 0; i < 8; ++i) {
        acc[i][0] = be0; acc[i][1] = be1; acc[i][2] = be2; acc[i][3] = be3;
    }

    for (int kq = 0; kq < 20; ++kq) {
        f32x4 A4[8];
#pragma unroll
        for (int i = 0; i < 8; ++i)
            A4[i] = *reinterpret_cast<const f32x4*>(&A[(rg + 16 * i) * 84 + kq * 4]);
        f32x4 W0 = *reinterpret_cast<const f32x4*>(&W[(kq * 4 + 0) * 64 + c0]);
        f32x4 W1 = *reinterpret_cast<const f32x4*>(&W[(kq * 4 + 1) * 64 + c0]);
        f32x4 W2 = *reinterpret_cast<const f32x4*>(&W[(kq * 4 + 2) * 64 + c0]);
        f32x4 W3 = *reinterpret_cast<const f32x4*>(&W[(kq * 4 + 3) * 64 + c0]);
#pragma unroll
        for (int i = 0; i < 8; ++i) {
#pragma unroll
            for (int j = 0; j < 4; ++j) {
                acc[i][j] += A4[i][0] * W0[j] + A4[i][1] * W1[j]
                           + A4[i][2] * W2[j] + A4[i][3] * W3[j];
            }
        }
    }

#pragma unroll
    for (int i = 0; i < 8; ++i) {
        int t = rg + 16 * i;
        unsigned int lo = (unsigned)f2bf(acc[i][0]) | ((unsigned)f2bf(acc[i][1]) << 16);
        unsigned int hi = (unsigned)f2bf(acc[i][2]) | ((unsigned)f2bf(acc[i][3]) << 16);
        *reinterpret_cast<uint2*>(x + ((size_t)t * BB + b) * DD + c0) = make_uint2(lo, hi);
    }
}

// ---------------- BN partial stats from bf16 x: p[t][slice][64] -------------
__global__ void stats_x(const unsigned short* __restrict__ x,
                        float* __restrict__ p1, float* __restrict__ p2) {
    int t = blockIdx.x, s = blockIdx.y;
    int tid = threadIdx.x;
    int dg = tid & 15, bl = tid >> 4;
    int d0 = dg * 4;
    float s1[4] = {0, 0, 0, 0}, s2[4] = {0, 0, 0, 0};
    const unsigned short* xt = x + (size_t)t * BB * DD;
    for (int it = 0; it < 32; ++it) {
        int b = s * 512 + it * 16 + bl;
        uint2 v = *reinterpret_cast<const uint2*>(xt + (size_t)b * DD + d0);
        const unsigned short* u = reinterpret_cast<const unsigned short*>(&v);
#pragma unroll
        for (int q = 0; q < 4; ++q) {
            float xv = bf2f(u[q]);
            s1[q] += xv; s2[q] += xv * xv;
        }
    }
    __shared__ float r1[16][64];
    __shared__ float r2[16][64];
#pragma unroll
    for (int q = 0; q < 4; ++q) { r1[bl][d0 + q] = s1[q]; r2[bl][d0 + q] = s2[q]; }
    __syncthreads();
    if (tid < 64) {
        float a = 0.f, b2 = 0.f;
        for (int g = 0; g < 16; ++g) { a += r1[g][tid]; b2 += r2[g][tid]; }
        size_t o = ((size_t)t * 8 + s) * 64 + tid;
        p1[o] = a; p2[o] = b2;
    }
}

// ---------------- BN stats finalize: a = rstd*scale, bb = bias - m*a ---------
__global__ void bn_stats(const float* __restrict__ p1, const float* __restrict__ p2,
                         const float* __restrict__ scale, const float* __restrict__ bias,
                         float* __restrict__ sa, float* __restrict__ sb) {
    int t = blockIdx.x, d = threadIdx.x;  // 64 threads
    float s1 = 0.f, s2 = 0.f;
    for (int c = 0; c < 8; ++c) {
        size_t o = ((size_t)t * 8 + c) * 64 + d;
        s1 += p1[o]; s2 += p2[o];
    }
    float m   = s1 * (1.0f / 4096.0f);
    float var = s2 * (1.0f / 4096.0f) - m * m;
    float a   = rsqrtf(var + 1e-5f) * scale[d];
    sa[t * 64 + d] = a;
    sb[t * 64 + d] = bias[d] - m * a;
}

// ---------------- fused LSTM: block owns 32 batch rows, NO cross-block dep ---
// grid 128 blocks x 512 threads (8 waves). Wave w owns u-slice w*32..+31 for
// all 4 gates. h lives in LDS (A's k=64..319 region), c in registers.
// Per step: k-loop MFMA over A[32][320] -> barrier -> gates -> write h_t back
// to LDS + stage prefetched x_{t+1} -> barrier.
__global__ void __launch_bounds__(512)
lstm_fused(const unsigned short* __restrict__ x, const unsigned short* __restrict__ wt,
           const float* __restrict__ sa, const float* __restrict__ sb,
           unsigned short* __restrict__ hf, const float* __restrict__ b_lstm) {
    __shared__ __align__(16) unsigned short A[32 * ASTR];

    int bid = blockIdx.x;
    int R0  = bid * 32;                 // first batch row owned by this block
    int tid = threadIdx.x;
    int lane = tid & 63, w = tid >> 6;  // wave 0..7
    int l15 = lane & 15, lhi = lane >> 4;
    int u0 = w * 32 + l15;              // hidden col base (s adds 16)

    // gate biases for this thread's two columns
    float bl[4][2];
#pragma unroll
    for (int g = 0; g < 4; ++g) {
        bl[g][0] = b_lstm[g * 256 + u0];
        bl[g][1] = b_lstm[g * 256 + u0 + 16];
    }

    // ---- init: zero h region (k=64..319), stage x_0 with BN fold ----
    {
        uint4 z = make_uint4(0, 0, 0, 0);
#pragma unroll
        for (int i = 0; i < 2; ++i) {
            int idx = tid + i * 512;    // < 1024 = 32 rows * 32 octs
            int row = idx >> 5, oct = idx & 31;
            *reinterpret_cast<uint4*>(&A[row * ASTR + 64 + oct * 8]) = z;
        }
    }
    int xrow = tid >> 3, xoct = tid & 7, d0x = (tid & 7) * 8;
    if (tid < 256) {
        f32x4 a0 = *reinterpret_cast<const f32x4*>(sa + d0x);
        f32x4 a1 = *reinterpret_cast<const f32x4*>(sa + d0x + 4);
        f32x4 b0 = *reinterpret_cast<const f32x4*>(sb + d0x);
        f32x4 b1 = *reinterpret_cast<const f32x4*>(sb + d0x + 4);
        uint4 v = *reinterpret_cast<const uint4*>(x + ((size_t)0 * BB + R0 + xrow) * DD + d0x);
        unsigned short* uu = reinterpret_cast<unsigned short*>(&v);
#pragma unroll
        for (int q = 0; q < 4; ++q) {
            float y = a0[q] * bf2f(uu[q]) + b0[q];
            uu[q] = f2bf(y >= 0.f ? y : 0.2f * y);
            float y2 = a1[q] * bf2f(uu[4 + q]) + b1[q];
            uu[4 + q] = f2bf(y2 >= 0.f ? y2 : 0.2f * y2);
        }
        *reinterpret_cast<uint4*>(&A[xrow * ASTR + xoct * 8]) = v;
    }
    __syncthreads();

    // c state in registers: creg[m][s][r]
    float creg[2][2][4];
#pragma unroll
    for (int m = 0; m < 2; ++m)
#pragma unroll
        for (int s = 0; s < 2; ++s)
#pragma unroll
            for (int r = 0; r < 4; ++r) creg[m][s][r] = 0.f;

    const unsigned short* wb = wt + ((size_t)lhi * 1024 + u0) * 8;
    int aoff = l15 * ASTR + lhi * 8;

    for (int t = 0; t < TT; ++t) {
        // ---- prefetch x_{t+1} + BN coeffs (lands during k-loop) ----
        uint4 pf;
        f32x4 pa0, pa1, pb0, pb1;
        bool do_pf = (t + 1 < TT) && (tid < 256);
        if (do_pf) {
            pf  = *reinterpret_cast<const uint4*>(x + ((size_t)(t + 1) * BB + R0 + xrow) * DD + d0x);
            pa0 = *reinterpret_cast<const f32x4*>(sa + (t + 1) * 64 + d0x);
            pa1 = *reinterpret_cast<const f32x4*>(sa + (t + 1) * 64 + d0x + 4);
            pb0 = *reinterpret_cast<const f32x4*>(sb + (t + 1) * 64 + d0x);
            pb1 = *reinterpret_cast<const f32x4*>(sb + (t + 1) * 64 + d0x + 4);
        }

        // ---- k-loop: z = A @ W (A rows m*16+l15, cols g*256 + u0 + s*16) ----
        f32x4 acc[2][4][2];
#pragma unroll
        for (int m = 0; m < 2; ++m)
#pragma unroll
            for (int g = 0; g < 4; ++g)
#pragma unroll
                for (int s = 0; s < 2; ++s) acc[m][g][s] = (f32x4)0.f;

#pragma unroll
        for (int ko2 = 0; ko2 < 10; ++ko2) {
            bshort8 a0 = *reinterpret_cast<const bshort8*>(&A[aoff + ko2 * 32]);
            bshort8 a1 = *reinterpret_cast<const bshort8*>(&A[aoff + 16 * ASTR + ko2 * 32]);
            const unsigned short* wk = wb + (size_t)ko2 * 32768;
#pragma unroll
            for (int g = 0; g < 4; ++g) {
#pragma unroll
                for (int s = 0; s < 2; ++s) {
                    bshort8 b = *reinterpret_cast<const bshort8*>(wk + g * 2048 + s * 128);
                    acc[0][g][s] = __builtin_amdgcn_mfma_f32_16x16x32_bf16(a0, b, acc[0][g][s], 0, 0, 0);
                    acc[1][g][s] = __builtin_amdgcn_mfma_f32_16x16x32_bf16(a1, b, acc[1][g][s], 0, 0, 0);
                }
            }
        }
        __syncthreads();   // all waves done reading A

        // ---- gates + state update; write h_t back into A (or global at end) --
        bool last = (t == TT - 1);
#pragma unroll
        for (int m = 0; m < 2; ++m) {
#pragma unroll
            for (int s = 0; s < 2; ++s) {
                int us = u0 + s * 16;
#pragma unroll
                for (int r = 0; r < 4; ++r) {
                    int row = m * 16 + lhi * 4 + r;
                    float zi = acc[m][0][s][r] + bl[0][s];
                    float zf = acc[m][1][s][r] + bl[1][s];
                    float zg = acc[m][2][s][r] + bl[2][s];
                    float zo = acc[m][3][s][r] + bl[3][s];
                    float si = 1.f / (1.f + __expf(-zi));
                    float sf = 1.f / (1.f + __expf(-zf));
                    float so = 1.f / (1.f + __expf(-zo));
                    float tg = 2.f / (1.f + __expf(-2.f * zg)) - 1.f;
                    float cn = sf * creg[m][s][r] + si * tg;
                    float tc = 2.f / (1.f + __expf(-2.f * cn)) - 1.f;
                    creg[m][s][r] = cn;
                    unsigned short hb = f2bf(so * tc);
                    if (last)
                        hf[(size_t)(R0 + row) * HH + us] = hb;
                    else
                        A[row * ASTR + 64 + us] = hb;
                }
            }
        }
        // ---- stage prefetched x_{t+1} with BN fold ----
        if (do_pf) {
            unsigned short* uu = reinterpret_cast<unsigned short*>(&pf);
#pragma unroll
            for (int q = 0; q < 4; ++q) {
                float y = pa0[q] * bf2f(uu[q]) + pb0[q];
                uu[q] = f2bf(y >= 0.f ? y : 0.2f * y);
                float y2 = pa1[q] * bf2f(uu[4 + q]) + pb1[q];
                uu[4 + q] = f2bf(y2 >= 0.f ? y2 : 0.2f * y2);
            }
            *reinterpret_cast<uint4*>(&A[xrow * ASTR + xoct * 8]) = pf;
        }
        __syncthreads();   // A ready for next step
    }
}

// ---------------- heads: mu = h@Wmu + bmu ; log_std clipped ------------------
__global__ void heads(const unsigned short* __restrict__ h,
                      const float* __restrict__ Wmu, const float* __restrict__ bmu,
                      const float* __restrict__ Wls, const float* __restrict__ bls,
                      float* __restrict__ out) {
    int tid = threadIdx.x;
    int b = blockIdx.x * 4 + (tid >> 6);
    int d = tid & 63;
    const unsigned short* hr = h + (size_t)b * HH;
    float mu = 0.f, ls = 0.f;
    for (int k = 0; k < HH; ++k) {
        float hv = bf2f(hr[k]);
        mu += hv * Wmu[k * 64 + d];
        ls += hv * Wls[k * 64 + d];
    }
    mu += bmu[d];
    ls += bls[d];
    ls = fminf(fmaxf(ls, -10.f), 2.f);
    out[(size_t)b * 64 + d] = mu;
    out[BD + (size_t)b * 64 + d] = ls;
}

extern "C" void kernel_launch(void* const* d_in, const int* in_sizes, int n_in,
                              void* d_out, int out_size, void* d_ws, size_t ws_size,
                              hipStream_t stream) {
    const float* obs = (const float*)d_in[0];
    const float* act = (const float*)d_in[1];
    const float* We  = (const float*)d_in[2];
    const float* be  = (const float*)d_in[3];
    const float* bns = (const float*)d_in[4];
    const float* bnb = (const float*)d_in[5];
    const float* Wx  = (const float*)d_in[6];
    const float* Wh  = (const float*)d_in[7];
    const float* bl  = (const float*)d_in[8];
    const float* Wmu = (const float*)d_in[9];
    const float* bmu = (const float*)d_in[10];
    const float* Wls = (const float*)d_in[11];
    const float* bls = (const float*)d_in[12];

    char* ws = (char*)d_ws;
    unsigned short* xbf = (unsigned short*)(ws + 0);            // 64MB (raw pre-BN bf16)
    unsigned short* wt  = (unsigned short*)(ws + 67108864);     // 640KB
    unsigned short* hfin= (unsigned short*)(ws + 67764224);     // 2MB (final h)
    float* p1           = (float*)(ws + 76152832);              // 256KB
    float* p2           = (float*)(ws + 78249984);              // 256KB
    float* sa           = (float*)(ws + 80347136);              // 32KB
    float* sb           = (float*)(ws + 80379904);              // 32KB

    pack_wt<<<1280, 256, 0, stream>>>(Wx, Wh, wt);
    embed_tiled<<<4096, 256, 0, stream>>>(obs, act, We, be, xbf);
    stats_x<<<dim3(128, 8), 256, 0, stream>>>(xbf, p1, p2);
    bn_stats<<<128, 64, 0, stream>>>(p1, p2, bns, bnb, sa, sb);

    lstm_fused<<<128, 512, 0, stream>>>(xbf, wt, sa, sb, hfin, bl);

    heads<<<1024, 256, 0, stream>>>(hfin, Wmu, bmu, Wls, bls, (float*)d_out);
}